// Round 4
// baseline (368.088 us; speedup 1.0000x reference)
//
#include <hip/hip_runtime.h>

#define S_LEN 2048
#define HID 4096
#define NH 32
#define NKV 8
#define HD 128
#define KVW 1024       // NKV*HD
#define NQKV 6144      // HID + 2*KVW

typedef _Float16 f16;
typedef _Float16 f16x8 __attribute__((ext_vector_type(8)));
typedef _Float16 f16x4 __attribute__((ext_vector_type(4)));
typedef float f32x4 __attribute__((ext_vector_type(4)));
typedef float f32x16 __attribute__((ext_vector_type(16)));
typedef unsigned int u32;
typedef u32 u32x4 __attribute__((ext_vector_type(4)));

__device__ __forceinline__ void gll16(const void* g, void* lds) {
  __builtin_amdgcn_global_load_lds((const __attribute__((address_space(1))) void*)g,
                                   (__attribute__((address_space(3))) void*)lds, 16, 0, 0);
}

// ---------------- cast hidden f32 -> f16 ----------------
__global__ void k_cast(const float* __restrict__ src, f16* __restrict__ dst) {
  size_t i = ((size_t)blockIdx.x * blockDim.x + threadIdx.x) * 8;
  float4 a = *(const float4*)(src + i);
  float4 b = *(const float4*)(src + i + 4);
  f16x8 o = { (f16)a.x, (f16)a.y, (f16)a.z, (f16)a.w,
              (f16)b.x, (f16)b.y, (f16)b.z, (f16)b.w };
  *(f16x8*)(dst + i) = o;
}

// ---------------- RoPE trig table: [S][64] float4 = (cos(2i), cos(2i+1), sin(2i), sin(2i+1))
__global__ void k_trig(float4* __restrict__ trig) {
  int id = blockIdx.x * blockDim.x + threadIdx.x;
  int s = id >> 6, i = id & 63;
  int j0 = 2 * i, j1 = 2 * i + 1;
  float f0 = powf(10000.f, -(float)(j0 & 63) / 64.f);
  float f1 = powf(10000.f, -(float)(j1 & 63) / 64.f);
  float a0 = (float)s * f0, a1 = (float)s * f1;
  trig[id] = make_float4(cosf(a0), cosf(a1), sinf(a0), sinf(a1));
}

// ---------------- transpose+cast: src f32 [4096][N] -> dst f16 [N][4096]
__global__ void k_transpose(const float* __restrict__ src, f16* __restrict__ dst, int N) {
  __shared__ f16 tile[64][72];
  int nb = blockIdx.x * 64, kb = blockIdx.y * 64;
  int t = threadIdx.x;
  int kl = t >> 4, nc = (t & 15) << 2;
#pragma unroll
  for (int p = 0; p < 4; ++p) {
    int kk = kl + p * 16;
    float4 v = *(const float4*)(src + (size_t)(kb + kk) * N + nb + nc);
    f16x4 h = { (f16)v.x, (f16)v.y, (f16)v.z, (f16)v.w };
    *(f16x4*)(&tile[kk][nc]) = h;
  }
  __syncthreads();
  int nl = t >> 3, c = t & 7;
#pragma unroll
  for (int p = 0; p < 2; ++p) {
    int nn = nl + p * 32;
    f16x8 o;
#pragma unroll
    for (int i = 0; i < 8; ++i) o[i] = tile[c * 8 + i][nn];
    *(f16x8*)(dst + (size_t)(nb + nn) * HID + kb + c * 8) = o;
  }
}

// ---------------- 256-row deep-pipelined GEMM: 4-slot ring, counted vmcnt ----------------
// BM=256, BK=32 hk-tiles, 8 waves (2M x 4N), wave tile 128 x BNW. LDS: 4 slots x 32KB.
// Slot layout: A[256][32] f16 (64B rows) @0, B[256][32] @16KB. Fragment reads are
// contiguous 1KB per wave -> conflict-free, no swizzle. Prefetch t+2 while computing t;
// end-of-tile s_waitcnt vmcnt(4) (never 0 in steady state) + one s_barrier.
// MODE 0: A=H, Bt=[wq^T;wk^T;wv^T] (BNW=48, grid 32x8): RoPE->Qr/Kr, V^T->Vt
// MODE 1: A=AO, Bt=wo^T (BNW=64, grid 16x8x2 split-K): f32 partials->Cout[z]
#define SLOT 32768
extern __shared__ char smem[];

template<int MODE, int BNW, int SPLITK>
__global__ __launch_bounds__(512, 2) void k_gemm2(
    const f16* __restrict__ A, const f16* __restrict__ Bt, int K,
    f16* __restrict__ Qr, f16* __restrict__ Kr, f16* __restrict__ Vt,
    const float4* __restrict__ trig, float* __restrict__ Cout)
{
  constexpr int BN = BNW * 4;
  constexpr int NF = BNW / 16;
  const int tid = threadIdx.x, ln = tid & 63, w = tid >> 6;
  const int la = ln & 15, lg = ln >> 4;
  const int wr = w >> 2, wc = w & 3;
  const int m0 = blockIdx.y * 256, n0 = blockIdx.x * BN;
  const int Ksub = K / SPLITK;
  const int NKT = Ksub / 32;
  const int koff = (SPLITK > 1) ? blockIdx.z * Ksub : 0;
  float* Cp = (SPLITK > 1) ? Cout + (size_t)blockIdx.z * (size_t)S_LEN * HID : Cout;

  // per-thread staging sources: 4 chunks of 1KB (chunks 0-15 = A rows, 16-31 = B rows)
  const char* gsrc[4];
  int ldst[4];
#pragma unroll
  for (int j = 0; j < 4; ++j) {
    int c = w * 4 + j;
    int rr = 16 * (c & 15) + (ln >> 2);
    int kq = ln & 3;
    size_t off;
    if (c < 16) {
      off = ((size_t)(m0 + rr) * K + koff + kq * 8) * 2;
      gsrc[j] = (const char*)A + off;
    } else {
      int br = (rr >= BN) ? rr - BN : rr;   // wrap pad rows (BN=192 case)
      off = ((size_t)(n0 + br) * K + koff + kq * 8) * 2;
      gsrc[j] = (const char*)Bt + off;
    }
    ldst[j] = c * 1024;
  }

  f32x4 acc[8][NF] = {};

  // prologue: stage tiles 0,1
#pragma unroll
  for (int j = 0; j < 4; ++j) gll16(gsrc[j], smem + 0 * SLOT + ldst[j]);
#pragma unroll
  for (int j = 0; j < 4; ++j) gll16(gsrc[j] + 64, smem + 1 * SLOT + ldst[j]);
  asm volatile("s_waitcnt vmcnt(4)" ::: "memory");
  __builtin_amdgcn_s_barrier();

  for (int t = 0; t < NKT; ++t) {
    if (t + 2 < NKT) {
      char* sb = smem + ((t + 2) & 3) * SLOT;
#pragma unroll
      for (int j = 0; j < 4; ++j)
        gll16(gsrc[j] + (size_t)(t + 2) * 64, sb + ldst[j]);
    }
    const char* sb = smem + (t & 3) * SLOT;
    f16x8 af[8], bf[NF];
#pragma unroll
    for (int i = 0; i < 8; ++i)
      af[i] = *(const f16x8*)(sb + (wr * 128 + i * 16 + la) * 64 + lg * 16);
#pragma unroll
    for (int n = 0; n < NF; ++n)
      bf[n] = *(const f16x8*)(sb + 16384 + (wc * BNW + n * 16 + la) * 64 + lg * 16);
    __builtin_amdgcn_s_setprio(1);
#pragma unroll
    for (int i = 0; i < 8; ++i)
#pragma unroll
      for (int n = 0; n < NF; ++n)
        acc[i][n] = __builtin_amdgcn_mfma_f32_16x16x32_f16(af[i], bf[n], acc[i][n], 0, 0, 0);
    __builtin_amdgcn_s_setprio(0);
    if (t + 2 < NKT) asm volatile("s_waitcnt vmcnt(4)" ::: "memory");
    else             asm volatile("s_waitcnt vmcnt(0)" ::: "memory");
    __builtin_amdgcn_s_barrier();
  }

  // ---- epilogue ----
#pragma unroll
  for (int mi = 0; mi < 8; ++mi) {
#pragma unroll
    for (int nf = 0; nf < NF; ++nf) {
      f32x4 fr = acc[mi][nf];
      int n = n0 + wc * BNW + nf * 16 + la;
      int mr = m0 + wr * 128 + mi * 16 + lg * 4;
      if (MODE == 0) {
        if (n < HID + KVW) {           // Q or K region -> RoPE
          int d = n & 127;
#pragma unroll
          for (int r = 0; r < 4; ++r) {
            float v = fr[r];
            float p = __shfl_xor(v, 1);
            float4 tc = trig[(size_t)(mr + r) * 64 + (d >> 1)];
            float cv = (d & 1) ? tc.y : tc.x;
            float sv = (d & 1) ? tc.w : tc.z;
            float o = v * cv + ((d & 1) ? p : -p) * sv;
            if (n < HID) Qr[(size_t)(mr + r) * HID + n] = (f16)o;
            else         Kr[(size_t)(mr + r) * KVW + (n - HID)] = (f16)o;
          }
        } else {                        // V region -> transposed store Vt[n][s]
          int nv = n - (HID + KVW);
          f16x4 o4 = { (f16)fr[0], (f16)fr[1], (f16)fr[2], (f16)fr[3] };
          *(f16x4*)(Vt + (size_t)nv * S_LEN + mr) = o4;
        }
      } else {
#pragma unroll
        for (int r = 0; r < 4; ++r)
          Cp[(size_t)(mr + r) * HID + n] = fr[r];
      }
    }
  }
}

// ---------------- split-K reduce: out = p0 + p1 (f32) ----------------
__global__ void k_reduce(const float* __restrict__ p0, const float* __restrict__ p1,
                         float* __restrict__ out) {
  size_t i = ((size_t)blockIdx.x * 256 + threadIdx.x) * 4;
  float4 a = *(const float4*)(p0 + i);
  float4 b = *(const float4*)(p1 + i);
  float4 o = make_float4(a.x + b.x, a.y + b.y, a.z + b.z, a.w + b.w);
  *(float4*)(out + i) = o;
}

// ---------------- flash attention, causal, GQA — swapped-QK^T 32x32 MFMA ----------------
#define KBYTES (64 * 128 * 2)   // 16KB K tile [64 kv][128 hd]
#define VBYTES (128 * 64 * 2)   // 16KB V tile [128 d][64 kv]

__global__ __launch_bounds__(256, 2) void k_attn(
    const f16* __restrict__ Qr, const f16* __restrict__ Kr, const f16* __restrict__ Vt,
    f16* __restrict__ AO)
{
  int bid = blockIdx.x;
  int h, c;
  if (bid < 256) { h = bid >> 3; c = bid & 7; }
  else           { int t = bid - 256; h = t >> 3; c = 15 - (t & 7); }
  const int hkv = h >> 2;
  const int q0c = c * 128;
  const int NT = 2 * c + 2;

  __shared__ char KV[2][KBYTES + VBYTES];   // 64KB total (double-buffered K+V)

  const int tid = threadIdx.x;
  const int ln = tid & 63, w = tid >> 6;
  const int q = ln & 31;            // q col within wave tile (C col = lane&31)
  const int hi = ln >> 5;
  const int qg = q0c + w * 32 + q;  // this lane's global q row

  size_t ksrc[4], vsrc[4];
  int kdo[4], vdo[4];
#pragma unroll
  for (int j = 0; j < 4; ++j) {
    int kc = w * 4 + j;                    // K chunk: 4 rows x 256B
    int kr = kc * 4 + (ln >> 4);           // kv row 0..63
    ksrc[j] = ((size_t)kr * KVW + hkv * HD) * 2 + (size_t)(((ln & 15) ^ (kr & 7)) * 16);
    kdo[j] = kc * 1024;
    int vc = w * 4 + j;                    // V chunk: 8 rows x 128B
    int d = vc * 8 + (ln >> 3);            // d row 0..127
    vsrc[j] = ((size_t)(hkv * HD + d) * S_LEN) * 2 + (size_t)(((ln & 7) ^ (d & 7)) * 16);
    vdo[j] = KBYTES + vc * 1024;
  }

  f16x8 qf[8];
  {
    const f16* qrow = Qr + (size_t)qg * HID + h * HD + hi * 8;
#pragma unroll
    for (int ks = 0; ks < 8; ++ks) qf[ks] = *(const f16x8*)(qrow + ks * 16);
  }

  f32x16 ot[4] = {};
  float m2 = -3.0e38f, l = 0.f;
  const float K2 = 0.12753256471f;  // log2(e)/sqrt(128)

  int buf = 0;
#pragma unroll
  for (int j = 0; j < 4; ++j) {
    gll16((const char*)Kr + ksrc[j], &KV[0][kdo[j]]);
    gll16((const char*)Vt + vsrc[j], &KV[0][vdo[j]]);
  }

  for (int jt = 0; jt < NT; ++jt) {
    __syncthreads();                       // tile jt staged & visible
    if (jt + 1 < NT) {                     // prefetch jt+1 into other buffer
      size_t ko = (size_t)(jt + 1) * 64 * KVW * 2;
      size_t vo = (size_t)(jt + 1) * 64 * 2;
#pragma unroll
      for (int j = 0; j < 4; ++j) {
        gll16((const char*)Kr + ksrc[j] + ko, &KV[buf ^ 1][kdo[j]]);
        gll16((const char*)Vt + vsrc[j] + vo, &KV[buf ^ 1][vdo[j]]);
      }
    }
    const int j0 = jt * 64;
    if (j0 <= q0c + w * 32 + 31) {         // wave has unmasked rows this tile
      const f16* Kb = (const f16*)&KV[buf][0];
      const f16* Vb = (const f16*)&KV[buf][KBYTES];
      f32x16 s0 = {}, s1 = {};
#pragma unroll
      for (int ks = 0; ks < 8; ++ks) {
        int cc = ((ks * 2 + hi) ^ (q & 7)) * 8;
        f16x8 k0 = *(const f16x8*)(Kb + q * 128 + cc);
        f16x8 k1 = *(const f16x8*)(Kb + (q + 32) * 128 + cc);
        s0 = __builtin_amdgcn_mfma_f32_32x32x16_f16(k0, qf[ks], s0, 0, 0, 0);
        s1 = __builtin_amdgcn_mfma_f32_32x32x16_f16(k1, qf[ks], s1, 0, 0, 0);
      }
      const bool nm = (j0 + 63 > q0c + w * 32);
      float p0[16], p1[16];
      float mx = -3.0e38f;
#pragma unroll
      for (int r = 0; r < 16; ++r) {
        float a = s0[r], b = s1[r];
        if (nm) {
          int kvb = j0 + (r & 3) + 8 * (r >> 2) + 4 * hi;
          if (kvb > qg) a = -3.0e38f;
          if (kvb + 32 > qg) b = -3.0e38f;
        }
        p0[r] = a; p1[r] = b;
        mx = fmaxf(mx, fmaxf(a, b));
      }
      mx = fmaxf(mx, __shfl_xor(mx, 32));
      float m2c = mx * K2;
      int defer = (m2c <= m2 + 11.0f);     // T13 defer-max (exp2 domain)
      if (!__all(defer)) {
        float m2n = fmaxf(m2, m2c);
        float corr = exp2f(m2 - m2n);
        m2 = m2n; l *= corr;
#pragma unroll
        for (int t = 0; t < 4; ++t)
#pragma unroll
          for (int r = 0; r < 16; ++r) ot[t][r] *= corr;
      }
      float sum = 0.f;
#pragma unroll
      for (int r = 0; r < 16; ++r) {
        p0[r] = exp2f(__builtin_fmaf(p0[r], K2, -m2));
        p1[r] = exp2f(__builtin_fmaf(p1[r], K2, -m2));
        sum += p0[r] + p1[r];
      }
      l += sum + __shfl_xor(sum, 32);
      u32 pw0[8], pw1[8];
#pragma unroll
      for (int t = 0; t < 8; ++t) {
        pw0[t] = __builtin_bit_cast(u32, __builtin_amdgcn_cvt_pkrtz(p0[2 * t], p0[2 * t + 1]));
        pw1[t] = __builtin_bit_cast(u32, __builtin_amdgcn_cvt_pkrtz(p1[2 * t], p1[2 * t + 1]));
      }
      f16x8 pf[4];
#pragma unroll
      for (int ch = 0; ch < 2; ++ch) {
        const u32* pw = ch ? pw1 : pw0;
        u32 sx[8];
#pragma unroll
        for (int t = 0; t < 8; ++t) sx[t] = (u32)__shfl_xor((int)pw[t], 32);
        u32x4 fa = { hi ? sx[2] : pw[0], hi ? sx[3] : pw[1],
                     hi ? pw[2] : sx[0], hi ? pw[3] : sx[1] };
        u32x4 fb = { hi ? sx[6] : pw[4], hi ? sx[7] : pw[5],
                     hi ? pw[6] : sx[4], hi ? pw[7] : sx[5] };
        pf[ch * 2 + 0] = __builtin_bit_cast(f16x8, fa);
        pf[ch * 2 + 1] = __builtin_bit_cast(f16x8, fb);
      }
#pragma unroll
      for (int dt = 0; dt < 4; ++dt) {
        int d = dt * 32 + q;
#pragma unroll
        for (int f = 0; f < 4; ++f) {
          f16x8 vf = *(const f16x8*)(Vb + d * 64 + (((f * 2 + hi) ^ (q & 7)) * 8));
          ot[dt] = __builtin_amdgcn_mfma_f32_32x32x16_f16(vf, pf[f], ot[dt], 0, 0, 0);
        }
      }
    }
    buf ^= 1;
  }

  __syncthreads();
  char* scr = &KV[0][0] + w * 8192;   // 32 rows x 256B per wave
  float inv = 1.f / l;
#pragma unroll
  for (int dt = 0; dt < 4; ++dt) {
#pragma unroll
    for (int rg = 0; rg < 4; ++rg) {
      u32 wa = __builtin_bit_cast(u32, __builtin_amdgcn_cvt_pkrtz(ot[dt][rg * 4 + 0] * inv, ot[dt][rg * 4 + 1] * inv));
      u32 wb = __builtin_bit_cast(u32, __builtin_amdgcn_cvt_pkrtz(ot[dt][rg * 4 + 2] * inv, ot[dt][rg * 4 + 3] * inv));
      int byte = q * 256 + (((dt * 4 + rg) ^ (q & 7)) * 16) + hi * 8;
      u32* p = (u32*)(scr + byte);
      p[0] = wa; p[1] = wb;
    }
  }
  asm volatile("s_waitcnt lgkmcnt(0)" ::: "memory");
#pragma unroll
  for (int ps = 0; ps < 8; ++ps) {
    int qr = ps * 4 + (ln >> 4);
    int ck = (ln & 15) ^ (qr & 7);
    f16x8 v = *(const f16x8*)(scr + qr * 256 + ck * 16);
    *(f16x8*)(AO + (size_t)(q0c + w * 32 + qr) * HID + h * HD + (ln & 15) * 8) = v;
  }
}

extern "C" void kernel_launch(void* const* d_in, const int* in_sizes, int n_in,
                              void* d_out, int out_size, void* d_ws, size_t ws_size,
                              hipStream_t stream) {
  const float* hs = (const float*)d_in[0];
  // d_in[1] = attention_mask (pure causal; handled analytically)
  const float* wq = (const float*)d_in[2];
  const float* wk = (const float*)d_in[3];
  const float* wv = (const float*)d_in[4];
  const float* wo = (const float*)d_in[5];
  float* out = (float*)d_out;

  char* ws = (char*)d_ws;
  size_t off = 0;
  auto alloc = [&](size_t b) { char* p = ws + off; off += (b + 255) & ~(size_t)255; return p; };
  // layout: [Hh, Wt, trig, Qrp, Krp, Vtp] get overwritten by split-K partials after attn
  f16* Hh   = (f16*)alloc((size_t)S_LEN * HID * 2);
  f16* Wt   = (f16*)alloc((size_t)NQKV * HID * 2);
  float4* trig = (float4*)alloc((size_t)S_LEN * 64 * sizeof(float4));
  f16* Qrp  = (f16*)alloc((size_t)S_LEN * HID * 2);
  f16* Krp  = (f16*)alloc((size_t)S_LEN * KVW * 2);
  f16* Vtp  = (f16*)alloc((size_t)KVW * S_LEN * 2);
  f16* AO   = (f16*)alloc((size_t)S_LEN * HID * 2);
  f16* Wot  = (f16*)alloc((size_t)HID * HID * 2);
  float* Pk = (float*)ws;   // 2 x 2048*4096 f32 partials over dead [Hh..Vtp] region

  hipFuncSetAttribute((const void*)k_gemm2<0, 48, 1>,
                      hipFuncAttributeMaxDynamicSharedMemorySize, 131072);
  hipFuncSetAttribute((const void*)k_gemm2<1, 64, 2>,
                      hipFuncAttributeMaxDynamicSharedMemorySize, 131072);

  k_cast<<<(S_LEN * HID) / (256 * 8), 256, 0, stream>>>(hs, Hh);
  k_trig<<<(S_LEN * 64) / 256, 256, 0, stream>>>(trig);
  k_transpose<<<dim3(HID / 64, HID / 64), 256, 0, stream>>>(wq, Wt, HID);
  k_transpose<<<dim3(KVW / 64, HID / 64), 256, 0, stream>>>(wk, Wt + (size_t)HID * HID, KVW);
  k_transpose<<<dim3(KVW / 64, HID / 64), 256, 0, stream>>>(wv, Wt + (size_t)(HID + KVW) * HID, KVW);
  k_transpose<<<dim3(HID / 64, HID / 64), 256, 0, stream>>>(wo, Wot, HID);
  k_gemm2<0, 48, 1><<<dim3(NQKV / 192, S_LEN / 256, 1), 512, 131072, stream>>>(
      Hh, Wt, HID, Qrp, Krp, Vtp, trig, nullptr);
  k_attn<<<dim3(512), 256, 0, stream>>>(Qrp, Krp, Vtp, AO);
  k_gemm2<1, 64, 2><<<dim3(HID / 256, S_LEN / 256, 2), 512, 131072, stream>>>(
      AO, Wot, HID, nullptr, nullptr, nullptr, nullptr, Pk);
  k_reduce<<<(S_LEN * HID) / (256 * 4), 256, 0, stream>>>(
      Pk, Pk + (size_t)S_LEN * HID, out);
}

// Round 5
// 364.702 us; speedup vs baseline: 1.0093x; 1.0093x over previous
//
#include <hip/hip_runtime.h>

#define S_LEN 2048
#define HID 4096
#define NH 32
#define NKV 8
#define HD 128
#define KVW 1024       // NKV*HD
#define NQKV 6144      // HID + 2*KVW

typedef _Float16 f16;
typedef _Float16 f16x8 __attribute__((ext_vector_type(8)));
typedef _Float16 f16x4 __attribute__((ext_vector_type(4)));
typedef float f32x4 __attribute__((ext_vector_type(4)));
typedef float f32x16 __attribute__((ext_vector_type(16)));
typedef unsigned int u32;
typedef u32 u32x4 __attribute__((ext_vector_type(4)));

__device__ __forceinline__ void gll16(const void* g, void* lds) {
  __builtin_amdgcn_global_load_lds((const __attribute__((address_space(1))) void*)g,
                                   (__attribute__((address_space(3))) void*)lds, 16, 0, 0);
}

// ---------------- cast hidden f32 -> f16 ----------------
__global__ void k_cast(const float* __restrict__ src, f16* __restrict__ dst) {
  size_t i = ((size_t)blockIdx.x * blockDim.x + threadIdx.x) * 8;
  float4 a = *(const float4*)(src + i);
  float4 b = *(const float4*)(src + i + 4);
  f16x8 o = { (f16)a.x, (f16)a.y, (f16)a.z, (f16)a.w,
              (f16)b.x, (f16)b.y, (f16)b.z, (f16)b.w };
  *(f16x8*)(dst + i) = o;
}

// ---------------- RoPE trig table: [S][64] float4 = (cos(2i), cos(2i+1), sin(2i), sin(2i+1))
__global__ void k_trig(float4* __restrict__ trig) {
  int id = blockIdx.x * blockDim.x + threadIdx.x;
  int s = id >> 6, i = id & 63;
  int j0 = 2 * i, j1 = 2 * i + 1;
  float f0 = powf(10000.f, -(float)(j0 & 63) / 64.f);
  float f1 = powf(10000.f, -(float)(j1 & 63) / 64.f);
  float a0 = (float)s * f0, a1 = (float)s * f1;
  trig[id] = make_float4(cosf(a0), cosf(a1), sinf(a0), sinf(a1));
}

// ---------------- transpose+cast: src f32 [4096][N] -> dst f16 [N][4096]
__global__ void k_transpose(const float* __restrict__ src, f16* __restrict__ dst, int N) {
  __shared__ f16 tile[64][72];
  int nb = blockIdx.x * 64, kb = blockIdx.y * 64;
  int t = threadIdx.x;
  int kl = t >> 4, nc = (t & 15) << 2;
#pragma unroll
  for (int p = 0; p < 4; ++p) {
    int kk = kl + p * 16;
    float4 v = *(const float4*)(src + (size_t)(kb + kk) * N + nb + nc);
    f16x4 h = { (f16)v.x, (f16)v.y, (f16)v.z, (f16)v.w };
    *(f16x4*)(&tile[kk][nc]) = h;
  }
  __syncthreads();
  int nl = t >> 3, c = t & 7;
#pragma unroll
  for (int p = 0; p < 2; ++p) {
    int nn = nl + p * 32;
    f16x8 o;
#pragma unroll
    for (int i = 0; i < 8; ++i) o[i] = tile[c * 8 + i][nn];
    *(f16x8*)(dst + (size_t)(nb + nn) * HID + kb + c * 8) = o;
  }
}

// ---------------- 256-row deep-pipelined GEMM: 4-slot ring, counted vmcnt ----------------
// BM=256, BK=32 hk-tiles, 8 waves (2M x 4N), wave tile 128 x BNW. LDS: 4 slots x 32KB.
// Slot layout: A[256][32] f16 (64B rows) @0, B[256][32] @16KB.
// Bank-conflict fix (R4 post-mortem): granule-XOR within each 64B row.
//   placement: LDS (row r, 16B-slot c') holds global granule c' ^ ((r>>1)&3)
//   staging:   lane ln loads granule (ln&3) ^ ((ln>>3)&3)      [same 64B lines, permuted]
//   reads:     col byte = (lg ^ ((la>>1)&3)) * 16
// -> per-16-lane group: 8 distinct bank-starts x 2 lanes = 2-way = free (m136).
// Prefetch t+2 while computing t; end-of-tile s_waitcnt vmcnt(4) (never 0 in steady
// state) + one s_barrier.
#define SLOT 32768
extern __shared__ char smem[];

template<int MODE, int BNW, int SPLITK>
__global__ __launch_bounds__(512, 2) void k_gemm2(
    const f16* __restrict__ A, const f16* __restrict__ Bt, int K,
    f16* __restrict__ Qr, f16* __restrict__ Kr, f16* __restrict__ Vt,
    const float4* __restrict__ trig, float* __restrict__ Cout)
{
  constexpr int BN = BNW * 4;
  constexpr int NF = BNW / 16;
  const int tid = threadIdx.x, ln = tid & 63, w = tid >> 6;
  const int la = ln & 15, lg = ln >> 4;
  const int wr = w >> 2, wc = w & 3;
  const int m0 = blockIdx.y * 256, n0 = blockIdx.x * BN;
  const int Ksub = K / SPLITK;
  const int NKT = Ksub / 32;
  const int koff = (SPLITK > 1) ? blockIdx.z * Ksub : 0;
  float* Cp = (SPLITK > 1) ? Cout + (size_t)blockIdx.z * (size_t)S_LEN * HID : Cout;

  // per-thread staging sources: 4 chunks of 1KB (chunks 0-15 = A rows, 16-31 = B rows)
  const char* gsrc[4];
  int ldst[4];
  const int kq = (ln & 3) ^ ((ln >> 3) & 3);   // granule swizzle (see header comment)
#pragma unroll
  for (int j = 0; j < 4; ++j) {
    int c = w * 4 + j;
    int rr = 16 * (c & 15) + (ln >> 2);
    size_t off;
    if (c < 16) {
      off = ((size_t)(m0 + rr) * K + koff + kq * 8) * 2;
      gsrc[j] = (const char*)A + off;
    } else {
      int br = (rr >= BN) ? rr - BN : rr;   // wrap pad rows (BN=192 case)
      off = ((size_t)(n0 + br) * K + koff + kq * 8) * 2;
      gsrc[j] = (const char*)Bt + off;
    }
    ldst[j] = c * 1024;
  }

  f32x4 acc[8][NF] = {};
  const int rcol = (lg ^ ((la >> 1) & 3)) * 16;  // fragment-read column byte

  // prologue: stage tiles 0,1
#pragma unroll
  for (int j = 0; j < 4; ++j) gll16(gsrc[j], smem + 0 * SLOT + ldst[j]);
#pragma unroll
  for (int j = 0; j < 4; ++j) gll16(gsrc[j] + 64, smem + 1 * SLOT + ldst[j]);
  asm volatile("s_waitcnt vmcnt(4)" ::: "memory");
  __builtin_amdgcn_s_barrier();

  for (int t = 0; t < NKT; ++t) {
    if (t + 2 < NKT) {
      char* sb = smem + ((t + 2) & 3) * SLOT;
#pragma unroll
      for (int j = 0; j < 4; ++j)
        gll16(gsrc[j] + (size_t)(t + 2) * 64, sb + ldst[j]);
    }
    const char* sb = smem + (t & 3) * SLOT;
    f16x8 af[8], bf[NF];
#pragma unroll
    for (int i = 0; i < 8; ++i)
      af[i] = *(const f16x8*)(sb + (wr * 128 + i * 16 + la) * 64 + rcol);
#pragma unroll
    for (int n = 0; n < NF; ++n)
      bf[n] = *(const f16x8*)(sb + 16384 + (wc * BNW + n * 16 + la) * 64 + rcol);
    __builtin_amdgcn_s_setprio(1);
#pragma unroll
    for (int i = 0; i < 8; ++i)
#pragma unroll
      for (int n = 0; n < NF; ++n)
        acc[i][n] = __builtin_amdgcn_mfma_f32_16x16x32_f16(af[i], bf[n], acc[i][n], 0, 0, 0);
    __builtin_amdgcn_s_setprio(0);
    if (t + 2 < NKT) asm volatile("s_waitcnt vmcnt(4)" ::: "memory");
    else             asm volatile("s_waitcnt vmcnt(0)" ::: "memory");
    __builtin_amdgcn_s_barrier();
  }

  // ---- epilogue ----
#pragma unroll
  for (int mi = 0; mi < 8; ++mi) {
#pragma unroll
    for (int nf = 0; nf < NF; ++nf) {
      f32x4 fr = acc[mi][nf];
      int n = n0 + wc * BNW + nf * 16 + la;
      int mr = m0 + wr * 128 + mi * 16 + lg * 4;
      if (MODE == 0) {
        if (n < HID + KVW) {           // Q or K region -> RoPE
          int d = n & 127;
#pragma unroll
          for (int r = 0; r < 4; ++r) {
            float v = fr[r];
            float p = __shfl_xor(v, 1);
            float4 tc = trig[(size_t)(mr + r) * 64 + (d >> 1)];
            float cv = (d & 1) ? tc.y : tc.x;
            float sv = (d & 1) ? tc.w : tc.z;
            float o = v * cv + ((d & 1) ? p : -p) * sv;
            if (n < HID) Qr[(size_t)(mr + r) * HID + n] = (f16)o;
            else         Kr[(size_t)(mr + r) * KVW + (n - HID)] = (f16)o;
          }
        } else {                        // V region -> transposed store Vt[n][s]
          int nv = n - (HID + KVW);
          f16x4 o4 = { (f16)fr[0], (f16)fr[1], (f16)fr[2], (f16)fr[3] };
          *(f16x4*)(Vt + (size_t)nv * S_LEN + mr) = o4;
        }
      } else {
#pragma unroll
        for (int r = 0; r < 4; ++r)
          Cp[(size_t)(mr + r) * HID + n] = fr[r];
      }
    }
  }
}

// ---------------- split-K reduce: out = p0 + p1 (f32) ----------------
__global__ void k_reduce(const float* __restrict__ p0, const float* __restrict__ p1,
                         float* __restrict__ out) {
  size_t i = ((size_t)blockIdx.x * 256 + threadIdx.x) * 4;
  float4 a = *(const float4*)(p0 + i);
  float4 b = *(const float4*)(p1 + i);
  float4 o = make_float4(a.x + b.x, a.y + b.y, a.z + b.z, a.w + b.w);
  *(float4*)(out + i) = o;
}

// ---------------- flash attention, causal, GQA — swapped-QK^T 32x32 MFMA ----------------
#define KBYTES (64 * 128 * 2)   // 16KB K tile [64 kv][128 hd]
#define VBYTES (128 * 64 * 2)   // 16KB V tile [128 d][64 kv]

__global__ __launch_bounds__(256, 2) void k_attn(
    const f16* __restrict__ Qr, const f16* __restrict__ Kr, const f16* __restrict__ Vt,
    f16* __restrict__ AO)
{
  int bid = blockIdx.x;
  int h, c;
  if (bid < 256) { h = bid >> 3; c = bid & 7; }
  else           { int t = bid - 256; h = t >> 3; c = 15 - (t & 7); }
  const int hkv = h >> 2;
  const int q0c = c * 128;
  const int NT = 2 * c + 2;

  __shared__ char KV[2][KBYTES + VBYTES];   // 64KB total (double-buffered K+V)

  const int tid = threadIdx.x;
  const int ln = tid & 63, w = tid >> 6;
  const int q = ln & 31;            // q col within wave tile (C col = lane&31)
  const int hi = ln >> 5;
  const int qg = q0c + w * 32 + q;  // this lane's global q row

  size_t ksrc[4], vsrc[4];
  int kdo[4], vdo[4];
#pragma unroll
  for (int j = 0; j < 4; ++j) {
    int kc = w * 4 + j;                    // K chunk: 4 rows x 256B
    int kr = kc * 4 + (ln >> 4);           // kv row 0..63
    ksrc[j] = ((size_t)kr * KVW + hkv * HD) * 2 + (size_t)(((ln & 15) ^ (kr & 7)) * 16);
    kdo[j] = kc * 1024;
    int vc = w * 4 + j;                    // V chunk: 8 rows x 128B
    int d = vc * 8 + (ln >> 3);            // d row 0..127
    vsrc[j] = ((size_t)(hkv * HD + d) * S_LEN) * 2 + (size_t)(((ln & 7) ^ (d & 7)) * 16);
    vdo[j] = KBYTES + vc * 1024;
  }

  f16x8 qf[8];
  {
    const f16* qrow = Qr + (size_t)qg * HID + h * HD + hi * 8;
#pragma unroll
    for (int ks = 0; ks < 8; ++ks) qf[ks] = *(const f16x8*)(qrow + ks * 16);
  }

  f32x16 ot[4] = {};
  float m2 = -3.0e38f, l = 0.f;
  const float K2 = 0.12753256471f;  // log2(e)/sqrt(128)

  int buf = 0;
#pragma unroll
  for (int j = 0; j < 4; ++j) {
    gll16((const char*)Kr + ksrc[j], &KV[0][kdo[j]]);
    gll16((const char*)Vt + vsrc[j], &KV[0][vdo[j]]);
  }

  for (int jt = 0; jt < NT; ++jt) {
    __syncthreads();                       // tile jt staged & visible
    if (jt + 1 < NT) {                     // prefetch jt+1 into other buffer
      size_t ko = (size_t)(jt + 1) * 64 * KVW * 2;
      size_t vo = (size_t)(jt + 1) * 64 * 2;
#pragma unroll
      for (int j = 0; j < 4; ++j) {
        gll16((const char*)Kr + ksrc[j] + ko, &KV[buf ^ 1][kdo[j]]);
        gll16((const char*)Vt + vsrc[j] + vo, &KV[buf ^ 1][vdo[j]]);
      }
    }
    const int j0 = jt * 64;
    if (j0 <= q0c + w * 32 + 31) {         // wave has unmasked rows this tile
      const f16* Kb = (const f16*)&KV[buf][0];
      const f16* Vb = (const f16*)&KV[buf][KBYTES];
      f32x16 s0 = {}, s1 = {};
#pragma unroll
      for (int ks = 0; ks < 8; ++ks) {
        int cc = ((ks * 2 + hi) ^ (q & 7)) * 8;
        f16x8 k0 = *(const f16x8*)(Kb + q * 128 + cc);
        f16x8 k1 = *(const f16x8*)(Kb + (q + 32) * 128 + cc);
        s0 = __builtin_amdgcn_mfma_f32_32x32x16_f16(k0, qf[ks], s0, 0, 0, 0);
        s1 = __builtin_amdgcn_mfma_f32_32x32x16_f16(k1, qf[ks], s1, 0, 0, 0);
      }
      const bool nm = (j0 + 63 > q0c + w * 32);
      float p0[16], p1[16];
      float mx = -3.0e38f;
#pragma unroll
      for (int r = 0; r < 16; ++r) {
        float a = s0[r], b = s1[r];
        if (nm) {
          int kvb = j0 + (r & 3) + 8 * (r >> 2) + 4 * hi;
          if (kvb > qg) a = -3.0e38f;
          if (kvb + 32 > qg) b = -3.0e38f;
        }
        p0[r] = a; p1[r] = b;
        mx = fmaxf(mx, fmaxf(a, b));
      }
      mx = fmaxf(mx, __shfl_xor(mx, 32));
      float m2c = mx * K2;
      int defer = (m2c <= m2 + 11.0f);     // T13 defer-max (exp2 domain)
      if (!__all(defer)) {
        float m2n = fmaxf(m2, m2c);
        float corr = exp2f(m2 - m2n);
        m2 = m2n; l *= corr;
#pragma unroll
        for (int t = 0; t < 4; ++t)
#pragma unroll
          for (int r = 0; r < 16; ++r) ot[t][r] *= corr;
      }
      float sum = 0.f;
#pragma unroll
      for (int r = 0; r < 16; ++r) {
        p0[r] = exp2f(__builtin_fmaf(p0[r], K2, -m2));
        p1[r] = exp2f(__builtin_fmaf(p1[r], K2, -m2));
        sum += p0[r] + p1[r];
      }
      l += sum + __shfl_xor(sum, 32);
      u32 pw0[8], pw1[8];
#pragma unroll
      for (int t = 0; t < 8; ++t) {
        pw0[t] = __builtin_bit_cast(u32, __builtin_amdgcn_cvt_pkrtz(p0[2 * t], p0[2 * t + 1]));
        pw1[t] = __builtin_bit_cast(u32, __builtin_amdgcn_cvt_pkrtz(p1[2 * t], p1[2 * t + 1]));
      }
      f16x8 pf[4];
#pragma unroll
      for (int ch = 0; ch < 2; ++ch) {
        const u32* pw = ch ? pw1 : pw0;
        u32 sx[8];
#pragma unroll
        for (int t = 0; t < 8; ++t) sx[t] = (u32)__shfl_xor((int)pw[t], 32);
        u32x4 fa = { hi ? sx[2] : pw[0], hi ? sx[3] : pw[1],
                     hi ? pw[2] : sx[0], hi ? pw[3] : sx[1] };
        u32x4 fb = { hi ? sx[6] : pw[4], hi ? sx[7] : pw[5],
                     hi ? pw[6] : sx[4], hi ? pw[7] : sx[5] };
        pf[ch * 2 + 0] = __builtin_bit_cast(f16x8, fa);
        pf[ch * 2 + 1] = __builtin_bit_cast(f16x8, fb);
      }
#pragma unroll
      for (int dt = 0; dt < 4; ++dt) {
        int d = dt * 32 + q;
#pragma unroll
        for (int f = 0; f < 4; ++f) {
          f16x8 vf = *(const f16x8*)(Vb + d * 64 + (((f * 2 + hi) ^ (q & 7)) * 8));
          ot[dt] = __builtin_amdgcn_mfma_f32_32x32x16_f16(vf, pf[f], ot[dt], 0, 0, 0);
        }
      }
    }
    buf ^= 1;
  }

  __syncthreads();
  char* scr = &KV[0][0] + w * 8192;   // 32 rows x 256B per wave
  float inv = 1.f / l;
#pragma unroll
  for (int dt = 0; dt < 4; ++dt) {
#pragma unroll
    for (int rg = 0; rg < 4; ++rg) {
      u32 wa = __builtin_bit_cast(u32, __builtin_amdgcn_cvt_pkrtz(ot[dt][rg * 4 + 0] * inv, ot[dt][rg * 4 + 1] * inv));
      u32 wb = __builtin_bit_cast(u32, __builtin_amdgcn_cvt_pkrtz(ot[dt][rg * 4 + 2] * inv, ot[dt][rg * 4 + 3] * inv));
      int byte = q * 256 + (((dt * 4 + rg) ^ (q & 7)) * 16) + hi * 8;
      u32* p = (u32*)(scr + byte);
      p[0] = wa; p[1] = wb;
    }
  }
  asm volatile("s_waitcnt lgkmcnt(0)" ::: "memory");
#pragma unroll
  for (int ps = 0; ps < 8; ++ps) {
    int qr = ps * 4 + (ln >> 4);
    int ck = (ln & 15) ^ (qr & 7);
    f16x8 v = *(const f16x8*)(scr + qr * 256 + ck * 16);
    *(f16x8*)(AO + (size_t)(q0c + w * 32 + qr) * HID + h * HD + (ln & 15) * 8) = v;
  }
}

extern "C" void kernel_launch(void* const* d_in, const int* in_sizes, int n_in,
                              void* d_out, int out_size, void* d_ws, size_t ws_size,
                              hipStream_t stream) {
  const float* hs = (const float*)d_in[0];
  // d_in[1] = attention_mask (pure causal; handled analytically)
  const float* wq = (const float*)d_in[2];
  const float* wk = (const float*)d_in[3];
  const float* wv = (const float*)d_in[4];
  const float* wo = (const float*)d_in[5];
  float* out = (float*)d_out;

  char* ws = (char*)d_ws;
  size_t off = 0;
  auto alloc = [&](size_t b) { char* p = ws + off; off += (b + 255) & ~(size_t)255; return p; };
  // layout: [Hh, Wt, trig, Qrp, Krp, Vtp] get overwritten by split-K partials after attn
  f16* Hh   = (f16*)alloc((size_t)S_LEN * HID * 2);
  f16* Wt   = (f16*)alloc((size_t)NQKV * HID * 2);
  float4* trig = (float4*)alloc((size_t)S_LEN * 64 * sizeof(float4));
  f16* Qrp  = (f16*)alloc((size_t)S_LEN * HID * 2);
  f16* Krp  = (f16*)alloc((size_t)S_LEN * KVW * 2);
  f16* Vtp  = (f16*)alloc((size_t)KVW * S_LEN * 2);
  f16* AO   = (f16*)alloc((size_t)S_LEN * HID * 2);
  f16* Wot  = (f16*)alloc((size_t)HID * HID * 2);
  float* Pk = (float*)ws;   // 2 x 2048*4096 f32 partials over dead [Hh..Vtp] region

  hipFuncSetAttribute((const void*)k_gemm2<0, 48, 1>,
                      hipFuncAttributeMaxDynamicSharedMemorySize, 131072);
  hipFuncSetAttribute((const void*)k_gemm2<1, 64, 2>,
                      hipFuncAttributeMaxDynamicSharedMemorySize, 131072);

  k_cast<<<(S_LEN * HID) / (256 * 8), 256, 0, stream>>>(hs, Hh);
  k_trig<<<(S_LEN * 64) / 256, 256, 0, stream>>>(trig);
  k_transpose<<<dim3(HID / 64, HID / 64), 256, 0, stream>>>(wq, Wt, HID);
  k_transpose<<<dim3(KVW / 64, HID / 64), 256, 0, stream>>>(wk, Wt + (size_t)HID * HID, KVW);
  k_transpose<<<dim3(KVW / 64, HID / 64), 256, 0, stream>>>(wv, Wt + (size_t)(HID + KVW) * HID, KVW);
  k_transpose<<<dim3(HID / 64, HID / 64), 256, 0, stream>>>(wo, Wot, HID);
  k_gemm2<0, 48, 1><<<dim3(NQKV / 192, S_LEN / 256, 1), 512, 131072, stream>>>(
      Hh, Wt, HID, Qrp, Krp, Vtp, trig, nullptr);
  k_attn<<<dim3(512), 256, 0, stream>>>(Qrp, Krp, Vtp, AO);
  k_gemm2<1, 64, 2><<<dim3(HID / 256, S_LEN / 256, 2), 512, 131072, stream>>>(
      AO, Wot, HID, nullptr, nullptr, nullptr, nullptr, Pk);
  k_reduce<<<(S_LEN * HID) / (256 * 4), 256, 0, stream>>>(
      Pk, Pk + (size_t)S_LEN * HID, out);
}

// Round 6
// 337.646 us; speedup vs baseline: 1.0902x; 1.0801x over previous
//
#include <hip/hip_runtime.h>

#define S_LEN 2048
#define HID 4096
#define NH 32
#define NKV 8
#define HD 128
#define KVW 1024       // NKV*HD
#define NQKV 6144      // HID + 2*KVW

typedef _Float16 f16;
typedef _Float16 f16x8 __attribute__((ext_vector_type(8)));
typedef _Float16 f16x4 __attribute__((ext_vector_type(4)));
typedef float f32x4 __attribute__((ext_vector_type(4)));
typedef float f32x16 __attribute__((ext_vector_type(16)));
typedef unsigned int u32;
typedef u32 u32x4 __attribute__((ext_vector_type(4)));

__device__ __forceinline__ void gll16(const void* g, void* lds) {
  __builtin_amdgcn_global_load_lds((const __attribute__((address_space(1))) void*)g,
                                   (__attribute__((address_space(3))) void*)lds, 16, 0, 0);
}
#define SFENCE asm volatile("" ::: "memory")

// ---------------- cast hidden f32 -> f16 ----------------
__global__ void k_cast(const float* __restrict__ src, f16* __restrict__ dst) {
  size_t i = ((size_t)blockIdx.x * blockDim.x + threadIdx.x) * 8;
  float4 a = *(const float4*)(src + i);
  float4 b = *(const float4*)(src + i + 4);
  f16x8 o = { (f16)a.x, (f16)a.y, (f16)a.z, (f16)a.w,
              (f16)b.x, (f16)b.y, (f16)b.z, (f16)b.w };
  *(f16x8*)(dst + i) = o;
}

// ---------------- RoPE trig table: [S][64] float4 = (cos(2i), cos(2i+1), sin(2i), sin(2i+1))
__global__ void k_trig(float4* __restrict__ trig) {
  int id = blockIdx.x * blockDim.x + threadIdx.x;
  int s = id >> 6, i = id & 63;
  int j0 = 2 * i, j1 = 2 * i + 1;
  float f0 = powf(10000.f, -(float)(j0 & 63) / 64.f);
  float f1 = powf(10000.f, -(float)(j1 & 63) / 64.f);
  float a0 = (float)s * f0, a1 = (float)s * f1;
  trig[id] = make_float4(cosf(a0), cosf(a1), sinf(a0), sinf(a1));
}

// ---------------- transpose+cast: src f32 [4096][N] -> dst f16 [N][4096]
__global__ void k_transpose(const float* __restrict__ src, f16* __restrict__ dst, int N) {
  __shared__ f16 tile[64][72];
  int nb = blockIdx.x * 64, kb = blockIdx.y * 64;
  int t = threadIdx.x;
  int kl = t >> 4, nc = (t & 15) << 2;
#pragma unroll
  for (int p = 0; p < 4; ++p) {
    int kk = kl + p * 16;
    float4 v = *(const float4*)(src + (size_t)(kb + kk) * N + nb + nc);
    f16x4 h = { (f16)v.x, (f16)v.y, (f16)v.z, (f16)v.w };
    *(f16x4*)(&tile[kk][nc]) = h;
  }
  __syncthreads();
  int nl = t >> 3, c = t & 7;
#pragma unroll
  for (int p = 0; p < 2; ++p) {
    int nn = nl + p * 32;
    f16x8 o;
#pragma unroll
    for (int i = 0; i < 8; ++i) o[i] = tile[c * 8 + i][nn];
    *(f16x8*)(dst + (size_t)(nb + nn) * HID + kb + c * 8) = o;
  }
}

// ---------------- 256-row 4-phase-per-K-tile GEMM (T3+T4+T5 rhythm) ----------------
// BM=256, BK=64, K=4096 (NT=64 tiles), 512 thr = 8 waves (2M x 4N), wave 128 x BNW.
// LDS rings: A: 4 half-slots x 16KB (half h of tile t -> slot (2t+h)&3) @0;
//            B: 2 slots x BN*128B (tile t -> slot t&1) @64KB.
// Phase q of tile t (quadrant = m-half x k-half, 12/8 MFMA, no frag re-reads):
//   ph1: stageA(t+1,h0) | read A m0-3 ks0 + B ks0 | bar | MFMA | bar
//   ph2: stageA(t+1,h1) | read A m4-7 ks0         | bar | MFMA | bar
//   ph3:                | read A m0-3 ks1 + B ks1 | bar | MFMA | bar
//   ph4: stageB(t+2)    | read A m4-7 ks1         | bar | MFMA | vmcnt(BGLD) bar
// Slot-liveness proof: A-half(wr) last ds_read at ph4 (lgkm-waited pre-MFMA, all waves
//   past closing barrier) -> slot (2t+h)&3 reused by t+2 whose stage issues at t+1.ph1/2
//   (after t's closing barrier). B last read ph3 -> slot t&1 reused by t+2 issued t.ph4.
// vmcnt: at tile end outstanding = [t+1.B(BGLD, issued t-1.ph4), t+1.Ah0(2), t+1.Ah1(2),
//   t+2.B(BGLD, just issued)] -> wait vmcnt(BGLD) drains exactly what tile t+1 needs,
//   keeps t+2.B in flight (never 0 in steady state).
// Swizzle (both sides, R5-verified): 128B rows, 16B slot c at row r holds k-granule
//   c^(r&7); staged via source-side XOR, read at (ks*4+lg)^(r&7). 0 conflicts.
extern __shared__ char smem[];

template<int MODE, int BNW>
__global__ __launch_bounds__(512, 2) void k_gemm3(
    const f16* __restrict__ A, const f16* __restrict__ Bt,
    f16* __restrict__ Qr, f16* __restrict__ Kr, f16* __restrict__ Vt,
    const float4* __restrict__ trig, float* __restrict__ Cout)
{
  constexpr int BN = BNW * 4;
  constexpr int NF = BNW / 16;
  constexpr int BGLD = BN / 64;          // B gloads per tile (8KB each)
  constexpr int BSLOT = BN * 128;        // B slot bytes
  constexpr int NT = 64;                 // K=4096 / BK=64
  const int tid = threadIdx.x, ln = tid & 63, w = tid >> 6;
  const int la = ln & 15, lg = ln >> 4;
  const int wr = w >> 2, wc = w & 3;
  const int m0 = blockIdx.y * 256, n0 = blockIdx.x * BN;

  // staging source pointers (tile 0); advance 128B per tile (64 f16)
  const char* AsrcH[2][2];
#pragma unroll
  for (int h = 0; h < 2; ++h)
#pragma unroll
    for (int g = 0; g < 2; ++g) {
      int r = h * 128 + g * 64 + w * 8 + (ln >> 3);
      AsrcH[h][g] = (const char*)A +
        ((size_t)(m0 + r) * HID + (size_t)(((ln & 7) ^ (r & 7)) * 8)) * 2;
    }
  const char* Bsrc[BGLD];
#pragma unroll
  for (int g = 0; g < BGLD; ++g) {
    int r = g * 64 + w * 8 + (ln >> 3);
    Bsrc[g] = (const char*)Bt +
      ((size_t)(n0 + r) * HID + (size_t)(((ln & 7) ^ (r & 7)) * 8)) * 2;
  }

  auto stageA = [&](int t, int h) {
    char* base = smem + (size_t)(((2 * t + h) & 3) * 16384) + w * 1024;
    gll16(AsrcH[h][0] + (size_t)t * 128, base);
    gll16(AsrcH[h][1] + (size_t)t * 128, base + 8192);
  };
  auto stageB = [&](int t) {
    char* base = smem + 65536 + (size_t)((t & 1) * BSLOT) + w * 1024;
#pragma unroll
    for (int g = 0; g < BGLD; ++g)
      gll16(Bsrc[g] + (size_t)t * 128, base + g * 8192);
  };
  auto ldA = [&](f16x8* dst, int t, int mh, int ks) {
    const char* sb = smem + (size_t)(((2 * t + wr) & 3) * 16384);
#pragma unroll
    for (int i = 0; i < 4; ++i) {
      int rl = (mh * 4 + i) * 16 + la;   // row within the wave's half-slot (0..127)
      dst[i] = *(const f16x8*)(sb + rl * 128 + (((ks * 4 + lg) ^ (rl & 7)) * 16));
    }
  };
  auto ldB = [&](f16x8* dst, int t, int ks) {
    const char* sb = smem + 65536 + (size_t)((t & 1) * BSLOT);
#pragma unroll
    for (int n = 0; n < NF; ++n) {
      int r = wc * BNW + n * 16 + la;
      dst[n] = *(const f16x8*)(sb + r * 128 + (((ks * 4 + lg) ^ (r & 7)) * 16));
    }
  };

  f32x4 acc[8][NF] = {};
  f16x8 a0[4], a1[4], b0[NF], b1[NF];

  // prologue: t0 fully + t1.B; wait leaves t1.B in flight
  stageA(0, 0); stageA(0, 1); stageB(0); stageB(1);
  if constexpr (BGLD == 3) asm volatile("s_waitcnt vmcnt(3)" ::: "memory");
  else                     asm volatile("s_waitcnt vmcnt(2)" ::: "memory");
  __builtin_amdgcn_s_barrier();

  for (int t = 0; t < NT; ++t) {
    // ---- ph1: (m0-3, ks0) ----
    if (t + 1 < NT) stageA(t + 1, 0);
    ldA(a0, t, 0, 0); ldB(b0, t, 0);
    SFENCE; __builtin_amdgcn_s_barrier();
    __builtin_amdgcn_s_setprio(1);
#pragma unroll
    for (int i = 0; i < 4; ++i)
#pragma unroll
      for (int n = 0; n < NF; ++n)
        acc[i][n] = __builtin_amdgcn_mfma_f32_16x16x32_f16(a0[i], b0[n], acc[i][n], 0, 0, 0);
    __builtin_amdgcn_s_setprio(0);
    SFENCE; __builtin_amdgcn_s_barrier();
    // ---- ph2: (m4-7, ks0) ----
    if (t + 1 < NT) stageA(t + 1, 1);
    ldA(a1, t, 1, 0);
    SFENCE; __builtin_amdgcn_s_barrier();
    __builtin_amdgcn_s_setprio(1);
#pragma unroll
    for (int i = 0; i < 4; ++i)
#pragma unroll
      for (int n = 0; n < NF; ++n)
        acc[4 + i][n] = __builtin_amdgcn_mfma_f32_16x16x32_f16(a1[i], b0[n], acc[4 + i][n], 0, 0, 0);
    __builtin_amdgcn_s_setprio(0);
    SFENCE; __builtin_amdgcn_s_barrier();
    // ---- ph3: (m0-3, ks1) ----
    ldA(a0, t, 0, 1); ldB(b1, t, 1);
    SFENCE; __builtin_amdgcn_s_barrier();
    __builtin_amdgcn_s_setprio(1);
#pragma unroll
    for (int i = 0; i < 4; ++i)
#pragma unroll
      for (int n = 0; n < NF; ++n)
        acc[i][n] = __builtin_amdgcn_mfma_f32_16x16x32_f16(a0[i], b1[n], acc[i][n], 0, 0, 0);
    __builtin_amdgcn_s_setprio(0);
    SFENCE; __builtin_amdgcn_s_barrier();
    // ---- ph4: (m4-7, ks1) ----
    if (t + 2 < NT) stageB(t + 2);
    ldA(a1, t, 1, 1);
    SFENCE; __builtin_amdgcn_s_barrier();
    __builtin_amdgcn_s_setprio(1);
#pragma unroll
    for (int i = 0; i < 4; ++i)
#pragma unroll
      for (int n = 0; n < NF; ++n)
        acc[4 + i][n] = __builtin_amdgcn_mfma_f32_16x16x32_f16(a1[i], b1[n], acc[4 + i][n], 0, 0, 0);
    __builtin_amdgcn_s_setprio(0);
    SFENCE;
    if (t < NT - 2) {
      if constexpr (BGLD == 3) asm volatile("s_waitcnt vmcnt(3)" ::: "memory");
      else                     asm volatile("s_waitcnt vmcnt(2)" ::: "memory");
    } else if (t == NT - 2) {
      asm volatile("s_waitcnt vmcnt(0)" ::: "memory");
    }
    __builtin_amdgcn_s_barrier();
  }

  // ---- epilogue ----
#pragma unroll
  for (int mi = 0; mi < 8; ++mi) {
#pragma unroll
    for (int nf = 0; nf < NF; ++nf) {
      f32x4 fr = acc[mi][nf];
      int n = n0 + wc * BNW + nf * 16 + la;
      int mr = m0 + wr * 128 + mi * 16 + lg * 4;
      if (MODE == 0) {
        if (n < HID + KVW) {           // Q or K region -> RoPE
          int d = n & 127;
#pragma unroll
          for (int r = 0; r < 4; ++r) {
            float v = fr[r];
            float p = __shfl_xor(v, 1);
            float4 tc = trig[(size_t)(mr + r) * 64 + (d >> 1)];
            float cv = (d & 1) ? tc.y : tc.x;
            float sv = (d & 1) ? tc.w : tc.z;
            float o = v * cv + ((d & 1) ? p : -p) * sv;
            if (n < HID) Qr[(size_t)(mr + r) * HID + n] = (f16)o;
            else         Kr[(size_t)(mr + r) * KVW + (n - HID)] = (f16)o;
          }
        } else {                        // V region -> transposed store Vt[n][s]
          int nv = n - (HID + KVW);
          f16x4 o4 = { (f16)fr[0], (f16)fr[1], (f16)fr[2], (f16)fr[3] };
          *(f16x4*)(Vt + (size_t)nv * S_LEN + mr) = o4;
        }
      } else {
#pragma unroll
        for (int r = 0; r < 4; ++r)
          Cout[(size_t)(mr + r) * HID + n] = fr[r];
      }
    }
  }
}

// ---------------- flash attention, causal, GQA — swapped-QK^T 32x32 MFMA ----------------
#define KBYTES (64 * 128 * 2)   // 16KB K tile [64 kv][128 hd]
#define VBYTES (128 * 64 * 2)   // 16KB V tile [128 d][64 kv]

__global__ __launch_bounds__(256, 2) void k_attn(
    const f16* __restrict__ Qr, const f16* __restrict__ Kr, const f16* __restrict__ Vt,
    f16* __restrict__ AO)
{
  int bid = blockIdx.x;
  int h, c;
  if (bid < 256) { h = bid >> 3; c = bid & 7; }
  else           { int t = bid - 256; h = t >> 3; c = 15 - (t & 7); }
  const int hkv = h >> 2;
  const int q0c = c * 128;
  const int NT = 2 * c + 2;

  __shared__ char KV[2][KBYTES + VBYTES];   // 64KB total (double-buffered K+V)

  const int tid = threadIdx.x;
  const int ln = tid & 63, w = tid >> 6;
  const int q = ln & 31;            // q col within wave tile (C col = lane&31)
  const int hi = ln >> 5;
  const int qg = q0c + w * 32 + q;  // this lane's global q row

  size_t ksrc[4], vsrc[4];
  int kdo[4], vdo[4];
#pragma unroll
  for (int j = 0; j < 4; ++j) {
    int kc = w * 4 + j;                    // K chunk: 4 rows x 256B
    int kr = kc * 4 + (ln >> 4);           // kv row 0..63
    ksrc[j] = ((size_t)kr * KVW + hkv * HD) * 2 + (size_t)(((ln & 15) ^ (kr & 7)) * 16);
    kdo[j] = kc * 1024;
    int vc = w * 4 + j;                    // V chunk: 8 rows x 128B
    int d = vc * 8 + (ln >> 3);            // d row 0..127
    vsrc[j] = ((size_t)(hkv * HD + d) * S_LEN) * 2 + (size_t)(((ln & 7) ^ (d & 7)) * 16);
    vdo[j] = KBYTES + vc * 1024;
  }

  f16x8 qf[8];
  {
    const f16* qrow = Qr + (size_t)qg * HID + h * HD + hi * 8;
#pragma unroll
    for (int ks = 0; ks < 8; ++ks) qf[ks] = *(const f16x8*)(qrow + ks * 16);
  }

  f32x16 ot[4] = {};
  float m2 = -3.0e38f, l = 0.f;
  const float K2 = 0.12753256471f;  // log2(e)/sqrt(128)

  int buf = 0;
#pragma unroll
  for (int j = 0; j < 4; ++j) {
    gll16((const char*)Kr + ksrc[j], &KV[0][kdo[j]]);
    gll16((const char*)Vt + vsrc[j], &KV[0][vdo[j]]);
  }

  for (int jt = 0; jt < NT; ++jt) {
    __syncthreads();                       // tile jt staged & visible
    if (jt + 1 < NT) {                     // prefetch jt+1 into other buffer
      size_t ko = (size_t)(jt + 1) * 64 * KVW * 2;
      size_t vo = (size_t)(jt + 1) * 64 * 2;
#pragma unroll
      for (int j = 0; j < 4; ++j) {
        gll16((const char*)Kr + ksrc[j] + ko, &KV[buf ^ 1][kdo[j]]);
        gll16((const char*)Vt + vsrc[j] + vo, &KV[buf ^ 1][vdo[j]]);
      }
    }
    const int j0 = jt * 64;
    if (j0 <= q0c + w * 32 + 31) {         // wave has unmasked rows this tile
      const f16* Kb = (const f16*)&KV[buf][0];
      const f16* Vb = (const f16*)&KV[buf][KBYTES];
      f32x16 s0 = {}, s1 = {};
#pragma unroll
      for (int ks = 0; ks < 8; ++ks) {
        int cc = ((ks * 2 + hi) ^ (q & 7)) * 8;
        f16x8 k0 = *(const f16x8*)(Kb + q * 128 + cc);
        f16x8 k1 = *(const f16x8*)(Kb + (q + 32) * 128 + cc);
        s0 = __builtin_amdgcn_mfma_f32_32x32x16_f16(k0, qf[ks], s0, 0, 0, 0);
        s1 = __builtin_amdgcn_mfma_f32_32x32x16_f16(k1, qf[ks], s1, 0, 0, 0);
      }
      const bool nm = (j0 + 63 > q0c + w * 32);
      float p0[16], p1[16];
      float mx = -3.0e38f;
#pragma unroll
      for (int r = 0; r < 16; ++r) {
        float a = s0[r], b = s1[r];
        if (nm) {
          int kvb = j0 + (r & 3) + 8 * (r >> 2) + 4 * hi;
          if (kvb > qg) a = -3.0e38f;
          if (kvb + 32 > qg) b = -3.0e38f;
        }
        p0[r] = a; p1[r] = b;
        mx = fmaxf(mx, fmaxf(a, b));
      }
      mx = fmaxf(mx, __shfl_xor(mx, 32));
      float m2c = mx * K2;
      int defer = (m2c <= m2 + 11.0f);     // T13 defer-max (exp2 domain)
      if (!__all(defer)) {
        float m2n = fmaxf(m2, m2c);
        float corr = exp2f(m2 - m2n);
        m2 = m2n; l *= corr;
#pragma unroll
        for (int t = 0; t < 4; ++t)
#pragma unroll
          for (int r = 0; r < 16; ++r) ot[t][r] *= corr;
      }
      float sum = 0.f;
#pragma unroll
      for (int r = 0; r < 16; ++r) {
        p0[r] = exp2f(__builtin_fmaf(p0[r], K2, -m2));
        p1[r] = exp2f(__builtin_fmaf(p1[r], K2, -m2));
        sum += p0[r] + p1[r];
      }
      l += sum + __shfl_xor(sum, 32);
      u32 pw0[8], pw1[8];
#pragma unroll
      for (int t = 0; t < 8; ++t) {
        pw0[t] = __builtin_bit_cast(u32, __builtin_amdgcn_cvt_pkrtz(p0[2 * t], p0[2 * t + 1]));
        pw1[t] = __builtin_bit_cast(u32, __builtin_amdgcn_cvt_pkrtz(p1[2 * t], p1[2 * t + 1]));
      }
      f16x8 pf[4];
#pragma unroll
      for (int ch = 0; ch < 2; ++ch) {
        const u32* pw = ch ? pw1 : pw0;
        u32 sx[8];
#pragma unroll
        for (int t = 0; t < 8; ++t) sx[t] = (u32)__shfl_xor((int)pw[t], 32);
        u32x4 fa = { hi ? sx[2] : pw[0], hi ? sx[3] : pw[1],
                     hi ? pw[2] : sx[0], hi ? pw[3] : sx[1] };
        u32x4 fb = { hi ? sx[6] : pw[4], hi ? sx[7] : pw[5],
                     hi ? pw[6] : sx[4], hi ? pw[7] : sx[5] };
        pf[ch * 2 + 0] = __builtin_bit_cast(f16x8, fa);
        pf[ch * 2 + 1] = __builtin_bit_cast(f16x8, fb);
      }
#pragma unroll
      for (int dt = 0; dt < 4; ++dt) {
        int d = dt * 32 + q;
#pragma unroll
        for (int f = 0; f < 4; ++f) {
          f16x8 vf = *(const f16x8*)(Vb + d * 64 + (((f * 2 + hi) ^ (q & 7)) * 8));
          ot[dt] = __builtin_amdgcn_mfma_f32_32x32x16_f16(vf, pf[f], ot[dt], 0, 0, 0);
        }
      }
    }
    buf ^= 1;
  }

  __syncthreads();
  char* scr = &KV[0][0] + w * 8192;   // 32 rows x 256B per wave
  float inv = 1.f / l;
#pragma unroll
  for (int dt = 0; dt < 4; ++dt) {
#pragma unroll
    for (int rg = 0; rg < 4; ++rg) {
      u32 wa = __builtin_bit_cast(u32, __builtin_amdgcn_cvt_pkrtz(ot[dt][rg * 4 + 0] * inv, ot[dt][rg * 4 + 1] * inv));
      u32 wb = __builtin_bit_cast(u32, __builtin_amdgcn_cvt_pkrtz(ot[dt][rg * 4 + 2] * inv, ot[dt][rg * 4 + 3] * inv));
      int byte = q * 256 + (((dt * 4 + rg) ^ (q & 7)) * 16) + hi * 8;
      u32* p = (u32*)(scr + byte);
      p[0] = wa; p[1] = wb;
    }
  }
  asm volatile("s_waitcnt lgkmcnt(0)" ::: "memory");
#pragma unroll
  for (int ps = 0; ps < 8; ++ps) {
    int qr = ps * 4 + (ln >> 4);
    int ck = (ln & 15) ^ (qr & 7);
    f16x8 v = *(const f16x8*)(scr + qr * 256 + ck * 16);
    *(f16x8*)(AO + (size_t)(q0c + w * 32 + qr) * HID + h * HD + (ln & 15) * 8) = v;
  }
}

extern "C" void kernel_launch(void* const* d_in, const int* in_sizes, int n_in,
                              void* d_out, int out_size, void* d_ws, size_t ws_size,
                              hipStream_t stream) {
  const float* hs = (const float*)d_in[0];
  // d_in[1] = attention_mask (pure causal; handled analytically)
  const float* wq = (const float*)d_in[2];
  const float* wk = (const float*)d_in[3];
  const float* wv = (const float*)d_in[4];
  const float* wo = (const float*)d_in[5];
  float* out = (float*)d_out;

  char* ws = (char*)d_ws;
  size_t off = 0;
  auto alloc = [&](size_t b) { char* p = ws + off; off += (b + 255) & ~(size_t)255; return p; };
  f16* Hh   = (f16*)alloc((size_t)S_LEN * HID * 2);
  f16* Wt   = (f16*)alloc((size_t)NQKV * HID * 2);
  float4* trig = (float4*)alloc((size_t)S_LEN * 64 * sizeof(float4));
  f16* Qrp  = (f16*)alloc((size_t)S_LEN * HID * 2);
  f16* Krp  = (f16*)alloc((size_t)S_LEN * KVW * 2);
  f16* Vtp  = (f16*)alloc((size_t)KVW * S_LEN * 2);
  f16* AO   = (f16*)alloc((size_t)S_LEN * HID * 2);
  f16* Wot  = (f16*)alloc((size_t)HID * HID * 2);

  hipFuncSetAttribute((const void*)k_gemm3<0, 48>,
                      hipFuncAttributeMaxDynamicSharedMemorySize, 131072);
  hipFuncSetAttribute((const void*)k_gemm3<1, 32>,
                      hipFuncAttributeMaxDynamicSharedMemorySize, 131072);

  k_cast<<<(S_LEN * HID) / (256 * 8), 256, 0, stream>>>(hs, Hh);
  k_trig<<<(S_LEN * 64) / 256, 256, 0, stream>>>(trig);
  k_transpose<<<dim3(HID / 64, HID / 64), 256, 0, stream>>>(wq, Wt, HID);
  k_transpose<<<dim3(KVW / 64, HID / 64), 256, 0, stream>>>(wk, Wt + (size_t)HID * HID, KVW);
  k_transpose<<<dim3(KVW / 64, HID / 64), 256, 0, stream>>>(wv, Wt + (size_t)(HID + KVW) * HID, KVW);
  k_transpose<<<dim3(HID / 64, HID / 64), 256, 0, stream>>>(wo, Wot, HID);
  // gemm<0>: N=6144, BN=192 -> grid 32x8 = 256 blocks (1/CU). LDS 112KB.
  k_gemm3<0, 48><<<dim3(NQKV / 192, S_LEN / 256), 512, 114688, stream>>>(
      Hh, Wt, Qrp, Krp, Vtp, trig, nullptr);
  k_attn<<<dim3(512), 256, 0, stream>>>(Qrp, Krp, Vtp, AO);
  // gemm<1>: N=4096, BN=128 -> grid 32x8 = 256 blocks, no split-K. LDS 96KB.
  k_gemm3<1, 32><<<dim3(HID / 128, S_LEN / 256), 512, 98304, stream>>>(
      AO, Wot, nullptr, nullptr, nullptr, nullptr, out);
}